// Round 1
// baseline (820.195 us; speedup 1.0000x reference)
//
#include <hip/hip_runtime.h>

// GAT spatio-temporal model, f32 reference-faithful implementation.
// B=8, N=512, Din=64, H=8, F=128, L=2.

constexpr int B = 8, N = 512, DIN = 64, H = 8, F = 128;
constexpr int BN = B * N;          // 4096
constexpr float ALPHA_LR = 0.2f;   // LeakyReLU slope
constexpr float NEGV = -9e15f;     // mask value
constexpr float EPS_LN = 1e-5f;
constexpr float FLOW = -3.0e38f;   // "-inf" substitute

__device__ __forceinline__ void fma4(float4& d, float a, const float4& b) {
  d.x = fmaf(a, b.x, d.x);
  d.y = fmaf(a, b.y, d.y);
  d.z = fmaf(a, b.z, d.z);
  d.w = fmaf(a, b.w, d.w);
}

// ---------------- input projection: h = relu(x @ Wp + bp) ----------------
// grid = BN blocks, block = 128 (one block per row, one thread per out col)
__global__ __launch_bounds__(128) void k_proj_in(
    const float* __restrict__ x, const float* __restrict__ Wp,
    const float* __restrict__ bp, float* __restrict__ h) {
  int row = blockIdx.x;
  int f = threadIdx.x;
  __shared__ float xr[DIN];
  if (threadIdx.x < DIN) xr[threadIdx.x] = x[(size_t)row * DIN + threadIdx.x];
  __syncthreads();
  float acc = bp[f];
#pragma unroll
  for (int i = 0; i < DIN; i++) acc = fmaf(xr[i], Wp[i * F + f], acc);
  h[(size_t)row * F + f] = fmaxf(acc, 0.f);
}

// ---------------- per-head projection: hh[b,h,n,f] = h[b,n,:] @ W[h] ------
// grid = (N/32, H, B), block = 256; 32-row x 128-col tile per block.
__global__ __launch_bounds__(256) void k_proj_heads(
    const float* __restrict__ h, const float* __restrict__ Wl,
    float* __restrict__ hh) {
  int tile = blockIdx.x, hd = blockIdx.y, b = blockIdx.z;
  int n0 = tile * 32;
  const float* W = Wl + (size_t)hd * F * F;
  __shared__ float At[32][132];  // padded: bank-conflict-free column reads
  __shared__ float Bt[32 * F];
  int tid = threadIdx.x;
  const float4* hg = (const float4*)(h + ((size_t)b * N + n0) * F);
#pragma unroll
  for (int k = 0; k < 4; k++) {
    int idx = tid + k * 256;
    int rr = idx >> 5, q = idx & 31;
    *(float4*)&At[rr][q * 4] = hg[idx];
  }
  int r = tid >> 3, c = tid & 7, f0 = c * 16;
  float4 acc[4] = {};
  for (int k0 = 0; k0 < F; k0 += 32) {
    __syncthreads();
    const float4* wg = (const float4*)(W + (size_t)k0 * F);
    float4* Bg = (float4*)Bt;
#pragma unroll
    for (int k = 0; k < 4; k++) Bg[tid + k * 256] = wg[tid + k * 256];
    __syncthreads();
#pragma unroll 8
    for (int kk = 0; kk < 32; kk++) {
      float a = At[r][k0 + kk];
      const float4* brow = (const float4*)&Bt[kk * F + f0];
      fma4(acc[0], a, brow[0]);
      fma4(acc[1], a, brow[1]);
      fma4(acc[2], a, brow[2]);
      fma4(acc[3], a, brow[3]);
    }
  }
  float4* o = (float4*)(hh + (((size_t)b * H + hd) * N + n0 + r) * F + f0);
  o[0] = acc[0]; o[1] = acc[1]; o[2] = acc[2]; o[3] = acc[3];
}

// ---------------- out projection: hs = multi[BN,1024] @ W_out[1024,128] ---
// grid = BN/32, block = 256
__global__ __launch_bounds__(256) void k_proj_out(
    const float* __restrict__ multi, const float* __restrict__ Wl,
    float* __restrict__ hs) {
  int row0 = blockIdx.x * 32;
  __shared__ float At[32][36];
  __shared__ float Bt[32 * F];
  int tid = threadIdx.x;
  int r = tid >> 3, c = tid & 7, f0 = c * 16;
  const int KT = H * F;  // 1024
  float4 acc[4] = {};
  for (int k0 = 0; k0 < KT; k0 += 32) {
    __syncthreads();
    {
      int rr = tid >> 3, q = tid & 7;
      *(float4*)&At[rr][q * 4] =
          *(const float4*)(multi + (size_t)(row0 + rr) * KT + k0 + q * 4);
    }
    const float4* wg = (const float4*)(Wl + (size_t)k0 * F);
    float4* Bg = (float4*)Bt;
#pragma unroll
    for (int k = 0; k < 4; k++) Bg[tid + k * 256] = wg[tid + k * 256];
    __syncthreads();
#pragma unroll 8
    for (int kk = 0; kk < 32; kk++) {
      float a = At[r][kk];
      const float4* brow = (const float4*)&Bt[kk * F + f0];
      fma4(acc[0], a, brow[0]);
      fma4(acc[1], a, brow[1]);
      fma4(acc[2], a, brow[2]);
      fma4(acc[3], a, brow[3]);
    }
  }
  float4* o = (float4*)(hs + (size_t)(row0 + r) * F + f0);
  o[0] = acc[0]; o[1] = acc[1]; o[2] = acc[2]; o[3] = acc[3];
}

// ---------------- s1/s2 = V . a1, V . a2 (wave per row) -------------------
// hmask=7: per-head a (rows are (b*H+h)*N+n, head = (row>>9)&7); hmask=0: single a.
__global__ __launch_bounds__(256) void k_s12(
    const float* __restrict__ v, const float* __restrict__ a,
    float* __restrict__ s1, float* __restrict__ s2, int hmask) {
  int lane = threadIdx.x & 63;
  int row = blockIdx.x * 4 + (threadIdx.x >> 6);
  const float* ah = a + (size_t)((row >> 9) & hmask) * (2 * F);
  const float* vp = v + (size_t)row * F;
  float x0 = vp[lane], x1 = vp[lane + 64];
  float p1 = fmaf(x0, ah[lane], x1 * ah[lane + 64]);
  float p2 = fmaf(x0, ah[F + lane], x1 * ah[F + lane + 64]);
#pragma unroll
  for (int off = 32; off > 0; off >>= 1) {
    p1 += __shfl_down(p1, off);
    p2 += __shfl_down(p2, off);
  }
  if (lane == 0) {
    s1[row] = p1;
    s2[row] = p2;
  }
}

// ---------------- fused flash attention, 8 heads, ELU epilogue ------------
// out layout: [B, N, H, F] (== multi [B,N,H*F]). grid = (N/32, H, B), 256 thr.
__global__ __launch_bounds__(256) void k_attn_heads(
    const float* __restrict__ hh, const float* __restrict__ s1g,
    const float* __restrict__ s2g, const int* __restrict__ adj,
    float* __restrict__ out) {
  int tile = blockIdx.x, hd = blockIdx.y, b = blockIdx.z;
  int n0 = tile * 32;
  int bh = b * H + hd;
  const float* V = hh + (size_t)bh * N * F;

  __shared__ float Vt[64 * F];
  __shared__ float S[32][65];
  __shared__ float s1r[32], mst[32], lst[32], alph[32], mnew[32];
  __shared__ float s2c[64];
  __shared__ float red[32][8];

  int tid = threadIdx.x;
  int r = tid >> 3, c = tid & 7, f0 = c * 16;
  if (tid < 32) {
    s1r[tid] = s1g[(size_t)bh * N + n0 + tid];
    mst[tid] = FLOW;
    lst[tid] = 0.f;
  }
  float4 acc[4] = {};
  for (int m0 = 0; m0 < N; m0 += 64) {
    __syncthreads();
    const float4* vg = (const float4*)(V + (size_t)m0 * F);
    float4* vl = (float4*)Vt;
#pragma unroll
    for (int k = 0; k < 8; k++) vl[tid + k * 256] = vg[tid + k * 256];
    if (tid < 64) s2c[tid] = s2g[(size_t)bh * N + m0 + tid];
    __syncthreads();
#pragma unroll
    for (int j = 0; j < 8; j++) {
      int idx = j * 256 + tid;
      int rr = idx >> 6, mm = idx & 63;
      int av = adj[((size_t)b * N + n0 + rr) * N + m0 + mm];
      float xv = s1r[rr] + s2c[mm];
      xv = xv > 0.f ? xv : ALPHA_LR * xv;
      S[rr][mm] = av > 0 ? xv : NEGV;
    }
    __syncthreads();
    float pm = FLOW;
#pragma unroll
    for (int k = 0; k < 8; k++) pm = fmaxf(pm, S[r][c * 8 + k]);
    red[r][c] = pm;
    __syncthreads();
    if (tid < 32) {
      float cm = red[tid][0];
#pragma unroll
      for (int k = 1; k < 8; k++) cm = fmaxf(cm, red[tid][k]);
      float nm = fmaxf(mst[tid], cm);
      alph[tid] = __expf(mst[tid] - nm);
      mnew[tid] = nm;
      mst[tid] = nm;
    }
    __syncthreads();
    float al = alph[r];
    float* accf = (float*)acc;
#pragma unroll
    for (int j = 0; j < 16; j++) accf[j] *= al;
    float nm = mnew[r];
    float lp = 0.f;
#pragma unroll
    for (int k = 0; k < 8; k++) {
      float p = __expf(S[r][c * 8 + k] - nm);
      S[r][c * 8 + k] = p;
      lp += p;
    }
    red[r][c] = lp;
    __syncthreads();
    if (tid < 32) {
      float ls = 0.f;
#pragma unroll
      for (int k = 0; k < 8; k++) ls += red[tid][k];
      lst[tid] = lst[tid] * alph[tid] + ls;
    }
#pragma unroll 4
    for (int m = 0; m < 64; m++) {
      float p = S[r][m];
      const float4* vrow = (const float4*)&Vt[m * F + f0];
      fma4(acc[0], p, vrow[0]);
      fma4(acc[1], p, vrow[1]);
      fma4(acc[2], p, vrow[2]);
      fma4(acc[3], p, vrow[3]);
    }
  }
  __syncthreads();
  float linv = 1.f / lst[r];
  float* accf = (float*)acc;
  float* o = out + (((size_t)b * N + n0 + r) * H + hd) * F + f0;
#pragma unroll
  for (int j = 0; j < 16; j++) {
    float v = accf[j] * linv;
    o[j] = v > 0.f ? v : __expf(v) - 1.f;  // ELU
  }
}

// ---------------- fused flash attention, single head, +residual ----------
// grid = (N/32, B), 256 thr. writes pre = att@hs + residual
__global__ __launch_bounds__(256) void k_attn_single(
    const float* __restrict__ hs, const float* __restrict__ s1g,
    const float* __restrict__ s2g, const int* __restrict__ adj,
    const float* __restrict__ resid, float* __restrict__ pre) {
  int tile = blockIdx.x, b = blockIdx.y;
  int n0 = tile * 32;
  const float* V = hs + (size_t)b * N * F;

  __shared__ float Vt[64 * F];
  __shared__ float S[32][65];
  __shared__ float s1r[32], mst[32], lst[32], alph[32], mnew[32];
  __shared__ float s2c[64];
  __shared__ float red[32][8];

  int tid = threadIdx.x;
  int r = tid >> 3, c = tid & 7, f0 = c * 16;
  if (tid < 32) {
    s1r[tid] = s1g[(size_t)b * N + n0 + tid];
    mst[tid] = FLOW;
    lst[tid] = 0.f;
  }
  float4 acc[4] = {};
  for (int m0 = 0; m0 < N; m0 += 64) {
    __syncthreads();
    const float4* vg = (const float4*)(V + (size_t)m0 * F);
    float4* vl = (float4*)Vt;
#pragma unroll
    for (int k = 0; k < 8; k++) vl[tid + k * 256] = vg[tid + k * 256];
    if (tid < 64) s2c[tid] = s2g[(size_t)b * N + m0 + tid];
    __syncthreads();
#pragma unroll
    for (int j = 0; j < 8; j++) {
      int idx = j * 256 + tid;
      int rr = idx >> 6, mm = idx & 63;
      int av = adj[((size_t)b * N + n0 + rr) * N + m0 + mm];
      float xv = s1r[rr] + s2c[mm];
      xv = xv > 0.f ? xv : ALPHA_LR * xv;
      S[rr][mm] = av > 0 ? xv : NEGV;
    }
    __syncthreads();
    float pm = FLOW;
#pragma unroll
    for (int k = 0; k < 8; k++) pm = fmaxf(pm, S[r][c * 8 + k]);
    red[r][c] = pm;
    __syncthreads();
    if (tid < 32) {
      float cm = red[tid][0];
#pragma unroll
      for (int k = 1; k < 8; k++) cm = fmaxf(cm, red[tid][k]);
      float nm = fmaxf(mst[tid], cm);
      alph[tid] = __expf(mst[tid] - nm);
      mnew[tid] = nm;
      mst[tid] = nm;
    }
    __syncthreads();
    float al = alph[r];
    float* accf = (float*)acc;
#pragma unroll
    for (int j = 0; j < 16; j++) accf[j] *= al;
    float nm = mnew[r];
    float lp = 0.f;
#pragma unroll
    for (int k = 0; k < 8; k++) {
      float p = __expf(S[r][c * 8 + k] - nm);
      S[r][c * 8 + k] = p;
      lp += p;
    }
    red[r][c] = lp;
    __syncthreads();
    if (tid < 32) {
      float ls = 0.f;
#pragma unroll
      for (int k = 0; k < 8; k++) ls += red[tid][k];
      lst[tid] = lst[tid] * alph[tid] + ls;
    }
#pragma unroll 4
    for (int m = 0; m < 64; m++) {
      float p = S[r][m];
      const float4* vrow = (const float4*)&Vt[m * F + f0];
      fma4(acc[0], p, vrow[0]);
      fma4(acc[1], p, vrow[1]);
      fma4(acc[2], p, vrow[2]);
      fma4(acc[3], p, vrow[3]);
    }
  }
  __syncthreads();
  float linv = 1.f / lst[r];
  size_t base = (((size_t)b * N + n0 + r) * F + f0);
  const float4* res4 = (const float4*)(resid + base);
  float4* o4 = (float4*)(pre + base);
#pragma unroll
  for (int q = 0; q < 4; q++) {
    float4 rv = res4[q];
    float4 a = acc[q];
    o4[q] = make_float4(fmaf(a.x, linv, rv.x), fmaf(a.y, linv, rv.y),
                        fmaf(a.z, linv, rv.z), fmaf(a.w, linv, rv.w));
  }
}

// ---------------- LayerNorm (+optional relu), wave per row ---------------
__global__ __launch_bounds__(256) void k_ln(
    const float* __restrict__ pre, const float* __restrict__ g,
    const float* __restrict__ bb, float* __restrict__ dst, int do_relu) {
  int lane = threadIdx.x & 63;
  int row = blockIdx.x * 4 + (threadIdx.x >> 6);
  const float* p = pre + (size_t)row * F;
  float x0 = p[lane], x1 = p[lane + 64];
  float s = x0 + x1, sq = fmaf(x0, x0, x1 * x1);
#pragma unroll
  for (int off = 32; off > 0; off >>= 1) {
    s += __shfl_down(s, off);
    sq += __shfl_down(sq, off);
  }
  s = __shfl(s, 0);
  sq = __shfl(sq, 0);
  float mu = s * (1.f / F);
  float var = sq * (1.f / F) - mu * mu;
  float rs = rsqrtf(var + EPS_LN);
  float y0 = fmaf((x0 - mu) * rs, g[lane], bb[lane]);
  float y1 = fmaf((x1 - mu) * rs, g[lane + 64], bb[lane + 64]);
  if (do_relu) {
    y0 = fmaxf(y0, 0.f);
    y1 = fmaxf(y1, 0.f);
  }
  dst[(size_t)row * F + lane] = y0;
  dst[(size_t)row * F + lane + 64] = y1;
}

extern "C" void kernel_launch(void* const* d_in, const int* in_sizes, int n_in,
                              void* d_out, int out_size, void* d_ws,
                              size_t ws_size, hipStream_t stream) {
  const float* x = (const float*)d_in[0];
  const int* adj = (const int*)d_in[1];
  const float* Wp = (const float*)d_in[2];
  const float* bp = (const float*)d_in[3];
  const float* W_heads = (const float*)d_in[4];
  const float* a_heads = (const float*)d_in[5];
  const float* W_out = (const float*)d_in[6];
  const float* a_out = (const float*)d_in[7];
  const float* ln_g = (const float*)d_in[8];
  const float* ln_b = (const float*)d_in[9];

  float* ws = (float*)d_ws;
  float* h = ws;      ws += (size_t)BN * F;          // [B,N,F]
  float* hh = ws;     ws += (size_t)B * H * N * F;   // [B,H,N,F]
  float* mult = ws;   ws += (size_t)B * H * N * F;   // [B,N,H,F]
  float* hs = ws;     ws += (size_t)BN * F;          // [B,N,F]
  float* pre = ws;    ws += (size_t)BN * F;          // [B,N,F]
  float* s1h = ws;    ws += (size_t)B * H * N;
  float* s2h = ws;    ws += (size_t)B * H * N;
  float* s1o = ws;    ws += (size_t)BN;
  float* s2o = ws;    ws += (size_t)BN;

  k_proj_in<<<BN, 128, 0, stream>>>(x, Wp, bp, h);
  for (int l = 0; l < 2; l++) {
    k_proj_heads<<<dim3(N / 32, H, B), 256, 0, stream>>>(
        h, W_heads + (size_t)l * H * F * F, hh);
    k_s12<<<(B * H * N) / 4, 256, 0, stream>>>(
        hh, a_heads + (size_t)l * H * 2 * F, s1h, s2h, 7);
    k_attn_heads<<<dim3(N / 32, H, B), 256, 0, stream>>>(hh, s1h, s2h, adj,
                                                         mult);
    k_proj_out<<<BN / 32, 256, 0, stream>>>(mult, W_out + (size_t)l * H * F * F,
                                            hs);
    k_s12<<<BN / 4, 256, 0, stream>>>(hs, a_out + (size_t)l * 2 * F, s1o, s2o,
                                      0);
    k_attn_single<<<dim3(N / 32, B), 256, 0, stream>>>(hs, s1o, s2o, adj, h,
                                                       pre);
    float* dst = (l == 0) ? h : (float*)d_out;
    k_ln<<<BN / 4, 256, 0, stream>>>(pre, ln_g + (size_t)l * F,
                                     ln_b + (size_t)l * F, dst, l == 0 ? 1 : 0);
  }
}

// Round 2
// 230.299 us; speedup vs baseline: 3.5614x; 3.5614x over previous
//
#include <hip/hip_runtime.h>

// GAT spatio-temporal model — bf16 MFMA implementation.
// B=8, N=512, Din=64, H=8, F=128, L=2.

constexpr int B = 8, N = 512, DIN = 64, H = 8, F = 128;
constexpr int BN = B * N;          // 4096
constexpr float ALPHA_LR = 0.2f;   // LeakyReLU slope
constexpr float NEGV = -9e15f;     // mask value
constexpr float EPS_LN = 1e-5f;
constexpr float FLOW = -3.0e38f;   // "-inf" substitute

typedef __attribute__((ext_vector_type(8))) short short8;  // 8 bf16
typedef __attribute__((ext_vector_type(4))) float f32x4;

__device__ __forceinline__ f32x4 mfma16(short8 a, short8 b, f32x4 c) {
  return __builtin_amdgcn_mfma_f32_16x16x32_bf16(a, b, c, 0, 0, 0);
}

__device__ __forceinline__ short f2bf(float f) {  // RNE f32 -> bf16 bits
  union { float f; unsigned u; } v;
  v.f = f;
  unsigned r = v.u + 0x7FFFu + ((v.u >> 16) & 1u);
  return (short)(r >> 16);
}
__device__ __forceinline__ float bf2f(short s) {
  union { unsigned u; float f; } v;
  v.u = ((unsigned)(unsigned short)s) << 16;
  return v.f;
}

// ---------- generic transpose: in f32 [bt][R][C] -> out bf16 [bt][C][R] ----
__global__ __launch_bounds__(256) void k_trans(
    const float* __restrict__ in, short* __restrict__ out, int R, int C) {
  __shared__ float T[32][33];
  int c0 = blockIdx.x * 32, r0 = blockIdx.y * 32, bt = blockIdx.z;
  const float* ip = in + (size_t)bt * R * C;
  short* op = out + (size_t)bt * R * C;
  int tid = threadIdx.x;
  {
    int r = tid >> 3, c4 = (tid & 7) * 4;
    float4 v = *(const float4*)(ip + (size_t)(r0 + r) * C + c0 + c4);
    T[r][c4] = v.x; T[r][c4 + 1] = v.y; T[r][c4 + 2] = v.z; T[r][c4 + 3] = v.w;
  }
  __syncthreads();
  {
    int cr = tid >> 3, q = (tid & 7) * 4;
    short4 o;
    o.x = f2bf(T[q][cr]); o.y = f2bf(T[q + 1][cr]);
    o.z = f2bf(T[q + 2][cr]); o.w = f2bf(T[q + 3][cr]);
    *(short4*)(op + (size_t)(c0 + cr) * R + r0 + q) = o;
  }
}

// ---------- adjacency -> 64-bit masks: amask[(b*N+n)*8 + chunk] ----------
__global__ __launch_bounds__(256) void k_adjmask(
    const int* __restrict__ adj, unsigned long long* __restrict__ amask) {
  int w = blockIdx.x * 4 + (threadIdx.x >> 6);
  int lane = threadIdx.x & 63;
  int v = adj[(size_t)w * 64 + lane];
  unsigned long long m = __ballot(v > 0);
  if (lane == 0) amask[w] = m;
}

// ---------- input projection: h = relu(x@Wp+bp), + bf16 copy -------------
__global__ __launch_bounds__(128) void k_proj_in(
    const float* __restrict__ x, const float* __restrict__ Wp,
    const float* __restrict__ bp, float* __restrict__ h,
    short* __restrict__ hb) {
  int row = blockIdx.x;
  int f = threadIdx.x;
  __shared__ float xr[DIN];
  if (threadIdx.x < DIN) xr[threadIdx.x] = x[(size_t)row * DIN + threadIdx.x];
  __syncthreads();
  float acc = bp[f];
#pragma unroll
  for (int i = 0; i < DIN; i++) acc = fmaf(xr[i], Wp[i * F + f], acc);
  acc = fmaxf(acc, 0.f);
  h[(size_t)row * F + f] = acc;
  hb[(size_t)row * F + f] = f2bf(acc);
}

// ---------- head projection: hhT[bh][f_out][n] = (WT[h] . hb^T) ----------
// grid (N/128, 2, B*H), block 256. A=WT rows(f_out) x k; B=hb rows(n) x k.
__global__ __launch_bounds__(256) void k_proj_heads_mfma(
    const short* __restrict__ WT, const short* __restrict__ hb,
    short* __restrict__ hhT) {
  int n0 = blockIdx.x * 128;
  int ft = blockIdx.y;
  int bh = blockIdx.z;
  int b = bh >> 3, hd = bh & 7;
  constexpr int LK = 136;  // padded K stride (bf16): 16B-aligned, 4-bank rot
  __shared__ short As[64 * LK];
  __shared__ short Bs[128 * LK];
  int tid = threadIdx.x, lane = tid & 63, w = tid >> 6;
  {  // stage A: 64 rows x 256B
    int r = tid >> 2, q = tid & 3;
    const uint4* g = (const uint4*)(WT + ((size_t)hd * F + ft * 64 + r) * F) + q * 4;
    uint4* lp = (uint4*)(As + r * LK) + q * 4;
    lp[0] = g[0]; lp[1] = g[1]; lp[2] = g[2]; lp[3] = g[3];
  }
  {  // stage B: 128 rows x 256B
    int q = tid & 3;
    for (int r = tid >> 2; r < 128; r += 64) {
      const uint4* g = (const uint4*)(hb + ((size_t)(b * N + n0 + r)) * F) + q * 4;
      uint4* lp = (uint4*)(Bs + r * LK) + q * 4;
      lp[0] = g[0]; lp[1] = g[1]; lp[2] = g[2]; lp[3] = g[3];
    }
  }
  __syncthreads();
  int arow = lane & 15, koff = (lane >> 4) * 8;
  f32x4 acc[4][2] = {};
#pragma unroll
  for (int ks = 0; ks < 4; ks++) {
    short8 a[4], bb[2];
#pragma unroll
    for (int rt = 0; rt < 4; rt++)
      a[rt] = *(const short8*)(As + (rt * 16 + arow) * LK + ks * 32 + koff);
#pragma unroll
    for (int cj = 0; cj < 2; cj++)
      bb[cj] = *(const short8*)(Bs + ((2 * w + cj) * 16 + arow) * LK + ks * 32 + koff);
#pragma unroll
    for (int rt = 0; rt < 4; rt++)
#pragma unroll
      for (int cj = 0; cj < 2; cj++)
        acc[rt][cj] = mfma16(a[rt], bb[cj], acc[rt][cj]);
  }
  short* outp = hhT + (size_t)bh * F * N;
  int crow0 = (lane >> 4) * 4, ccol = lane & 15;
#pragma unroll
  for (int rt = 0; rt < 4; rt++)
#pragma unroll
    for (int cj = 0; cj < 2; cj++) {
      int fo = ft * 64 + rt * 16 + crow0;
      int n = n0 + (2 * w + cj) * 16 + ccol;
#pragma unroll
      for (int r = 0; r < 4; r++)
        outp[(size_t)(fo + r) * N + n] = f2bf(acc[rt][cj][r]);
    }
}

// ---------- s1/s2 from transposed V: s = a^T . VT --------------------------
// grid (BH, N/256); hmask=7 for heads (a per head), 0 for single.
__global__ __launch_bounds__(256) void k_s12T(
    const short* __restrict__ VT, const float* __restrict__ a,
    float* __restrict__ s1, float* __restrict__ s2, int hmask) {
  int bh = blockIdx.x;
  int n = blockIdx.y * 256 + threadIdx.x;
  const float* ah = a + (size_t)(bh & hmask) * (2 * F);
  const short* vp = VT + (size_t)bh * F * N + n;
  float p1 = 0.f, p2 = 0.f;
#pragma unroll 8
  for (int f = 0; f < F; f++) {
    float v = bf2f(vp[(size_t)f * N]);
    p1 = fmaf(v, ah[f], p1);
    p2 = fmaf(v, ah[F + f], p2);
  }
  s1[(size_t)bh * N + n] = p1;
  s2[(size_t)bh * N + n] = p2;
}

// ---------- fused flash attention (MFMA). HEADS=1: 8-head, ELU -> multi bf16
// HEADS=0: single head, +resid -> pre f32. Block: 32 rows x 128 feats, 4 waves.
template <int HEADS>
__global__ __launch_bounds__(256) void k_attn_mfma(
    const short* __restrict__ VT, const float* __restrict__ s1g,
    const float* __restrict__ s2g, const unsigned long long* __restrict__ amask,
    const float* __restrict__ resid, void* __restrict__ outv) {
  int tile = blockIdx.x;
  int hd = HEADS ? blockIdx.y : 0;
  int b = blockIdx.z;
  int bh = HEADS ? b * H + hd : b;
  int n0 = tile * 32;
  constexpr int LVK = 72;  // VT row stride (64+8 bf16)
  __shared__ short Vs[128 * LVK];
  __shared__ short Pf[256 * 8];  // 4 A-fragments x 64 lanes x 8 bf16
  __shared__ float s2c[64];
  __shared__ unsigned long long smask[32];
  __shared__ float red[32][8];
  __shared__ float s1r[32], mrun[32], lrun[32], alph[32], mnew[32], linv[32];

  int tid = threadIdx.x, lane = tid & 63, w = tid >> 6;
  int srow = (tid >> 7) * 16 + (tid & 15);                   // S row 0..31
  int scol0 = ((tid >> 6) & 1) * 32 + ((tid >> 4) & 3) * 8;  // S col base
  int g = (tid >> 4) & 7;                                    // reduce group
  int arow = lane & 15, koff = (lane >> 4) * 8;

  if (tid < 32) {
    s1r[tid] = s1g[(size_t)bh * N + n0 + tid];
    mrun[tid] = FLOW;
    lrun[tid] = 0.f;
  }
  const short* Vg = VT + (size_t)bh * F * N;
  f32x4 acc[2][2] = {};

  for (int m0 = 0; m0 < N; m0 += 64) {
    __syncthreads();  // A: protect Vs/s2c/smask/Pf from prior-iter readers
    {
      int fr = tid >> 1, hf = tid & 1;
      const uint4* g4 = (const uint4*)(Vg + (size_t)fr * N + m0 + hf * 32);
      uint4* l4 = (uint4*)(Vs + fr * LVK + hf * 32);
      l4[0] = g4[0]; l4[1] = g4[1]; l4[2] = g4[2]; l4[3] = g4[3];
    }
    if (tid < 64) s2c[tid] = s2g[(size_t)bh * N + m0 + tid];
    if (tid < 32) smask[tid] = amask[((size_t)b * N + n0 + tid) * 8 + (m0 >> 6)];
    __syncthreads();  // B
    float x[8];
    {
      float s1v = s1r[srow];
      unsigned bits = (unsigned)((smask[srow] >> scol0) & 0xffull);
      float mx = FLOW;
#pragma unroll
      for (int j = 0; j < 8; j++) {
        float xv = s1v + s2c[scol0 + j];
        xv = xv > 0.f ? xv : ALPHA_LR * xv;
        xv = ((bits >> j) & 1u) ? xv : NEGV;
        x[j] = xv;
        mx = fmaxf(mx, xv);
      }
      red[srow][g] = mx;
    }
    __syncthreads();  // C
    if (tid < 32) {
      float cm = red[tid][0];
#pragma unroll
      for (int k = 1; k < 8; k++) cm = fmaxf(cm, red[tid][k]);
      float nm = fmaxf(mrun[tid], cm);
      alph[tid] = __expf(mrun[tid] - nm);
      mnew[tid] = nm;
      mrun[tid] = nm;
    }
    __syncthreads();  // D
    {
      float nm = mnew[srow], lp = 0.f;
      short8 pk;
#pragma unroll
      for (int j = 0; j < 8; j++) {
        float pv = __expf(x[j] - nm);
        lp += pv;
        pk[j] = f2bf(pv);
      }
      *(short8*)(Pf + tid * 8) = pk;  // exact A-fragment order
      red[srow][g] = lp;
    }
    __syncthreads();  // E
    if (tid < 32) {
      float ls = 0.f;
#pragma unroll
      for (int k = 0; k < 8; k++) ls += red[tid][k];
      lrun[tid] = lrun[tid] * alph[tid] + ls;
    }
    // rescale accumulators by per-row alpha
#pragma unroll
    for (int rt = 0; rt < 2; rt++) {
      f32x4 av = *(const f32x4*)(alph + rt * 16 + (lane >> 4) * 4);
#pragma unroll
      for (int cj = 0; cj < 2; cj++) {
        acc[rt][cj][0] *= av[0]; acc[rt][cj][1] *= av[1];
        acc[rt][cj][2] *= av[2]; acc[rt][cj][3] *= av[3];
      }
    }
    // MFMA: P (A-frags from Pf) x V^T (B-frags from Vs)
#pragma unroll
    for (int ks = 0; ks < 2; ks++) {
      short8 a0 = *(const short8*)(Pf + ((0 * 2 + ks) * 64 + lane) * 8);
      short8 a1 = *(const short8*)(Pf + ((1 * 2 + ks) * 64 + lane) * 8);
#pragma unroll
      for (int cj = 0; cj < 2; cj++) {
        short8 bb = *(const short8*)(Vs + ((2 * w + cj) * 16 + arow) * LVK +
                                     ks * 32 + koff);
        acc[0][cj] = mfma16(a0, bb, acc[0][cj]);
        acc[1][cj] = mfma16(a1, bb, acc[1][cj]);
      }
    }
  }
  __syncthreads();
  if (tid < 32) linv[tid] = 1.f / lrun[tid];
  __syncthreads();
  int crow0 = (lane >> 4) * 4, ccol = lane & 15;
  if (HEADS) {
    short* mout = (short*)outv;  // [B][N][H*F]
#pragma unroll
    for (int rt = 0; rt < 2; rt++)
#pragma unroll
      for (int cj = 0; cj < 2; cj++) {
        int fcol = (2 * w + cj) * 16 + ccol;
#pragma unroll
        for (int r = 0; r < 4; r++) {
          int nrow = rt * 16 + crow0 + r;
          float v = acc[rt][cj][r] * linv[nrow];
          v = v > 0.f ? v : __expf(v) - 1.f;  // ELU
          mout[((size_t)(b * N + n0 + nrow)) * (H * F) + hd * F + fcol] = f2bf(v);
        }
      }
  } else {
    float* preo = (float*)outv;  // [B][N][F]
#pragma unroll
    for (int rt = 0; rt < 2; rt++)
#pragma unroll
      for (int cj = 0; cj < 2; cj++) {
        int fcol = (2 * w + cj) * 16 + ccol;
#pragma unroll
        for (int r = 0; r < 4; r++) {
          int nrow = rt * 16 + crow0 + r;
          size_t idx = ((size_t)(b * N + n0 + nrow)) * F + fcol;
          preo[idx] = acc[rt][cj][r] * linv[nrow] + resid[idx];
        }
      }
  }
}

// ---------- out projection: hsT[b][f_out][n] = WoT . multi^T ---------------
// grid (4, 8, B), block 256. Tile 32 f_out x 64 n, K=1024 in 128-chunks.
__global__ __launch_bounds__(256) void k_proj_out_mfma(
    const short* __restrict__ WoT, const short* __restrict__ multi,
    short* __restrict__ hsT) {
  int ft = blockIdx.x, nt = blockIdx.y, b = blockIdx.z;
  constexpr int LK = 136;
  __shared__ short As[32 * LK];
  __shared__ short Bs[64 * LK];
  int tid = threadIdx.x, lane = tid & 63, w = tid >> 6;
  int arow = lane & 15, koff = (lane >> 4) * 8;
  const int KT = H * F;  // 1024
  f32x4 acc[2] = {};
  for (int k0 = 0; k0 < KT; k0 += 128) {
    __syncthreads();
    {  // A: 32 rows x 128 k
      int r = tid >> 3, e = tid & 7;
      const uint4* gp = (const uint4*)(WoT + (size_t)(ft * 32 + r) * KT + k0) + e * 2;
      uint4* lp = (uint4*)(As + r * LK) + e * 2;
      lp[0] = gp[0]; lp[1] = gp[1];
    }
    {  // B: 64 rows x 128 k
      int r = tid >> 2, q = tid & 3;
      const uint4* gp =
          (const uint4*)(multi + (size_t)(b * N + nt * 64 + r) * KT + k0) + q * 4;
      uint4* lp = (uint4*)(Bs + r * LK) + q * 4;
      lp[0] = gp[0]; lp[1] = gp[1]; lp[2] = gp[2]; lp[3] = gp[3];
    }
    __syncthreads();
#pragma unroll
    for (int ks = 0; ks < 4; ks++) {
      short8 b0 = *(const short8*)(Bs + (w * 16 + arow) * LK + ks * 32 + koff);
      short8 a0 = *(const short8*)(As + arow * LK + ks * 32 + koff);
      short8 a1 = *(const short8*)(As + (16 + arow) * LK + ks * 32 + koff);
      acc[0] = mfma16(a0, b0, acc[0]);
      acc[1] = mfma16(a1, b0, acc[1]);
    }
  }
  int crow0 = (lane >> 4) * 4, ccol = lane & 15;
  short* op = hsT + (size_t)b * F * N;
#pragma unroll
  for (int rt = 0; rt < 2; rt++)
#pragma unroll
    for (int r = 0; r < 4; r++)
      op[(size_t)(ft * 32 + rt * 16 + crow0 + r) * N + nt * 64 + w * 16 + ccol] =
          f2bf(acc[rt][r]);
}

// ---------- LayerNorm (+relu, +bf16 copy), wave per row ------------------
__global__ __launch_bounds__(256) void k_ln(
    const float* __restrict__ pre, const float* __restrict__ g,
    const float* __restrict__ bb, float* __restrict__ dst,
    short* __restrict__ dstb, int do_relu) {
  int lane = threadIdx.x & 63;
  int row = blockIdx.x * 4 + (threadIdx.x >> 6);
  const float* p = pre + (size_t)row * F;
  float x0 = p[lane], x1 = p[lane + 64];
  float s = x0 + x1, sq = fmaf(x0, x0, x1 * x1);
#pragma unroll
  for (int off = 32; off > 0; off >>= 1) {
    s += __shfl_down(s, off);
    sq += __shfl_down(sq, off);
  }
  s = __shfl(s, 0);
  sq = __shfl(sq, 0);
  float mu = s * (1.f / F);
  float var = sq * (1.f / F) - mu * mu;
  float rs = rsqrtf(var + EPS_LN);
  float y0 = fmaf((x0 - mu) * rs, g[lane], bb[lane]);
  float y1 = fmaf((x1 - mu) * rs, g[lane + 64], bb[lane + 64]);
  if (do_relu) {
    y0 = fmaxf(y0, 0.f);
    y1 = fmaxf(y1, 0.f);
  }
  dst[(size_t)row * F + lane] = y0;
  dst[(size_t)row * F + lane + 64] = y1;
  if (dstb) {
    dstb[(size_t)row * F + lane] = f2bf(y0);
    dstb[(size_t)row * F + lane + 64] = f2bf(y1);
  }
}

extern "C" void kernel_launch(void* const* d_in, const int* in_sizes, int n_in,
                              void* d_out, int out_size, void* d_ws,
                              size_t ws_size, hipStream_t stream) {
  const float* x = (const float*)d_in[0];
  const int* adj = (const int*)d_in[1];
  const float* Wp = (const float*)d_in[2];
  const float* bp = (const float*)d_in[3];
  const float* W_heads = (const float*)d_in[4];
  const float* a_heads = (const float*)d_in[5];
  const float* W_out = (const float*)d_in[6];
  const float* a_out = (const float*)d_in[7];
  const float* ln_g = (const float*)d_in[8];
  const float* ln_b = (const float*)d_in[9];

  char* p = (char*)d_ws;
  auto alloc = [&](size_t bytes) {
    char* r = p;
    p += (bytes + 255) & ~(size_t)255;
    return r;
  };
  short* WTh = (short*)alloc((size_t)2 * H * F * F * 2);
  short* WoT = (short*)alloc((size_t)2 * H * F * F * 2);
  unsigned long long* amask = (unsigned long long*)alloc((size_t)BN * 8 * 8);
  float* h = (float*)alloc((size_t)BN * F * 4);
  short* hb = (short*)alloc((size_t)BN * F * 2);
  short* hhT = (short*)alloc((size_t)B * H * F * N * 2);
  short* multi = (short*)alloc((size_t)BN * H * F * 2);
  short* hsT = (short*)alloc((size_t)B * F * N * 2);
  float* pre = (float*)alloc((size_t)BN * F * 4);
  float* s1h = (float*)alloc((size_t)B * H * N * 4);
  float* s2h = (float*)alloc((size_t)B * H * N * 4);
  float* s1o = (float*)alloc((size_t)BN * 4);
  float* s2o = (float*)alloc((size_t)BN * 4);

  k_trans<<<dim3(4, 4, 16), 256, 0, stream>>>(W_heads, WTh, 128, 128);
  k_trans<<<dim3(4, 32, 2), 256, 0, stream>>>(W_out, WoT, 1024, 128);
  k_adjmask<<<dim3(BN * 8 / 4), 256, 0, stream>>>(adj, amask);
  k_proj_in<<<dim3(BN), 128, 0, stream>>>(x, Wp, bp, h, hb);
  for (int l = 0; l < 2; l++) {
    k_proj_heads_mfma<<<dim3(4, 2, 64), 256, 0, stream>>>(
        WTh + (size_t)l * H * F * F, hb, hhT);
    k_s12T<<<dim3(64, 2), 256, 0, stream>>>(
        hhT, a_heads + (size_t)l * H * 2 * F, s1h, s2h, 7);
    k_attn_mfma<1><<<dim3(16, 8, 8), 256, 0, stream>>>(hhT, s1h, s2h, amask,
                                                       nullptr, multi);
    k_proj_out_mfma<<<dim3(4, 8, 8), 256, 0, stream>>>(
        WoT + (size_t)l * F * H * F, multi, hsT);
    k_s12T<<<dim3(8, 2), 256, 0, stream>>>(hsT, a_out + (size_t)l * 2 * F, s1o,
                                           s2o, 0);
    k_attn_mfma<0><<<dim3(16, 1, 8), 256, 0, stream>>>(hsT, s1o, s2o, amask, h,
                                                       pre);
    if (l == 0)
      k_ln<<<dim3(BN / 4), 256, 0, stream>>>(pre, ln_g, ln_b, h, hb, 1);
    else
      k_ln<<<dim3(BN / 4), 256, 0, stream>>>(pre, ln_g + F, ln_b + F,
                                             (float*)d_out, nullptr, 0);
  }
}

// Round 3
// 189.662 us; speedup vs baseline: 4.3245x; 1.2143x over previous
//
#include <hip/hip_runtime.h>

// GAT spatio-temporal model — bf16 MFMA, fused single-pass-softmax version.
// B=8, N=512, Din=64, H=8, F=128, L=2.

constexpr int B = 8, N = 512, DIN = 64, H = 8, F = 128;
constexpr int BN = B * N;          // 4096
constexpr float ALPHA_LR = 0.2f;   // LeakyReLU slope
constexpr float EPS_LN = 1e-5f;
constexpr float FLOW = -3.0e38f;   // "-inf" substitute

typedef __attribute__((ext_vector_type(8))) short short8;  // 8 bf16
typedef __attribute__((ext_vector_type(4))) float f32x4;

__device__ __forceinline__ f32x4 mfma16(short8 a, short8 b, f32x4 c) {
  return __builtin_amdgcn_mfma_f32_16x16x32_bf16(a, b, c, 0, 0, 0);
}

__device__ __forceinline__ short f2bf(float f) {  // RNE f32 -> bf16 bits
  union { float f; unsigned u; } v;
  v.f = f;
  unsigned r = v.u + 0x7FFFu + ((v.u >> 16) & 1u);
  return (short)(r >> 16);
}

// ================= fused setup: adjmask | proj_in | 2x weight transpose ====
// grid: [0,8192) adjmask, [8192,10240) proj_in (2 rows/blk), [10240,10496)
// W_heads transpose, [10496,10752) W_out transpose.
__global__ __launch_bounds__(256) void k_setup(
    const float* __restrict__ x, const int* __restrict__ adj,
    const float* __restrict__ Wp, const float* __restrict__ bp,
    const float* __restrict__ W_heads, const float* __restrict__ W_out,
    float* __restrict__ h, short* __restrict__ hb,
    unsigned long long* __restrict__ amask, short* __restrict__ WTh,
    short* __restrict__ WoT) {
  __shared__ float T[32][33];
  __shared__ float xr[2][64];
  int blk = blockIdx.x, tid = threadIdx.x;
  if (blk < 8192) {  // adjacency -> 64-bit masks
    int w = blk * 4 + (tid >> 6);
    int lane = tid & 63;
    int v = adj[(size_t)w * 64 + lane];
    unsigned long long m = __ballot(v > 0);
    if (lane == 0) amask[w] = m;
  } else if (blk < 10240) {  // input projection: h = relu(x@Wp+bp)
    int rb = blk - 8192;
    int half = tid >> 7, f = tid & 127;
    int row = rb * 2 + half;
    if (f < 64) xr[half][f] = x[(size_t)row * DIN + f];
    __syncthreads();
    float acc = bp[f];
#pragma unroll
    for (int i = 0; i < DIN; i++) acc = fmaf(xr[half][i], Wp[i * F + f], acc);
    acc = fmaxf(acc, 0.f);
    h[(size_t)row * F + f] = acc;
    hb[(size_t)row * F + f] = f2bf(acc);
  } else {  // transpose f32 [bt][R][C] -> bf16 [bt][C][R]
    const float* in;
    short* out;
    int R, C, bx, by, bt;
    if (blk < 10496) {
      int i = blk - 10240;
      in = W_heads; out = WTh; R = 128; C = 128;
      bx = i & 3; by = (i >> 2) & 3; bt = i >> 4;
    } else {
      int i = blk - 10496;
      in = W_out; out = WoT; R = 1024; C = 128;
      bx = i & 3; by = (i >> 2) & 31; bt = i >> 7;
    }
    int c0 = bx * 32, r0 = by * 32;
    const float* ip = in + (size_t)bt * R * C;
    short* op = out + (size_t)bt * R * C;
    {
      int r = tid >> 3, c4 = (tid & 7) * 4;
      float4 v = *(const float4*)(ip + (size_t)(r0 + r) * C + c0 + c4);
      T[r][c4] = v.x; T[r][c4 + 1] = v.y; T[r][c4 + 2] = v.z; T[r][c4 + 3] = v.w;
    }
    __syncthreads();
    {
      int cr = tid >> 3, q = (tid & 7) * 4;
      short4 o;
      o.x = f2bf(T[q][cr]); o.y = f2bf(T[q + 1][cr]);
      o.z = f2bf(T[q + 2][cr]); o.w = f2bf(T[q + 3][cr]);
      *(short4*)(op + (size_t)(c0 + cr) * R + r0 + q) = o;
    }
  }
}

// ========= head projection: hhT[bh][f_out][n] = WT[h] . hb^T, + s1/s2 =====
// grid (N/128, 2, B*H), block 256.
__global__ __launch_bounds__(256) void k_proj_heads_mfma(
    const short* __restrict__ WT, const short* __restrict__ hb,
    const float* __restrict__ ah_base, short* __restrict__ hhT,
    float* __restrict__ s1, float* __restrict__ s2) {
  int n0 = blockIdx.x * 128;
  int ft = blockIdx.y;
  int bh = blockIdx.z;
  int b = bh >> 3, hd = bh & 7;
  constexpr int LK = 136;
  __shared__ short As[64 * LK];
  __shared__ short Bs[128 * LK];
  int tid = threadIdx.x, lane = tid & 63, w = tid >> 6;
  {  // stage A: 64 rows x 256B
    int r = tid >> 2, q = tid & 3;
    const uint4* g = (const uint4*)(WT + ((size_t)hd * F + ft * 64 + r) * F) + q * 4;
    uint4* lp = (uint4*)(As + r * LK) + q * 4;
    lp[0] = g[0]; lp[1] = g[1]; lp[2] = g[2]; lp[3] = g[3];
  }
  {  // stage B: 128 rows x 256B
    int q = tid & 3;
    for (int r = tid >> 2; r < 128; r += 64) {
      const uint4* g = (const uint4*)(hb + ((size_t)(b * N + n0 + r)) * F) + q * 4;
      uint4* lp = (uint4*)(Bs + r * LK) + q * 4;
      lp[0] = g[0]; lp[1] = g[1]; lp[2] = g[2]; lp[3] = g[3];
    }
  }
  __syncthreads();
  int arow = lane & 15, koff = (lane >> 4) * 8;
  f32x4 acc[4][2] = {};
#pragma unroll
  for (int ks = 0; ks < 4; ks++) {
    short8 a[4], bb[2];
#pragma unroll
    for (int rt = 0; rt < 4; rt++)
      a[rt] = *(const short8*)(As + (rt * 16 + arow) * LK + ks * 32 + koff);
#pragma unroll
    for (int cj = 0; cj < 2; cj++)
      bb[cj] = *(const short8*)(Bs + ((2 * w + cj) * 16 + arow) * LK + ks * 32 + koff);
#pragma unroll
    for (int rt = 0; rt < 4; rt++)
#pragma unroll
      for (int cj = 0; cj < 2; cj++)
        acc[rt][cj] = mfma16(a[rt], bb[cj], acc[rt][cj]);
  }
  short* outp = hhT + (size_t)bh * F * N;
  int crow0 = (lane >> 4) * 4;
#pragma unroll
  for (int rt = 0; rt < 4; rt++)
#pragma unroll
    for (int cj = 0; cj < 2; cj++) {
      int fo = ft * 64 + rt * 16 + crow0;
      int n = n0 + (2 * w + cj) * 16 + arow;
#pragma unroll
      for (int r = 0; r < 4; r++)
        outp[(size_t)(fo + r) * N + n] = f2bf(acc[rt][cj][r]);
    }
  // fused s1/s2 epilogue: partial dot with attention vector, atomic into s1/s2
  const float* ah = ah_base + (size_t)hd * 2 * F;
  float pa1[2] = {0.f, 0.f}, pa2[2] = {0.f, 0.f};
#pragma unroll
  for (int rt = 0; rt < 4; rt++) {
    int fo = ft * 64 + rt * 16 + crow0;
#pragma unroll
    for (int r = 0; r < 4; r++) {
      float a1v = ah[fo + r], a2v = ah[F + fo + r];
      pa1[0] = fmaf(a1v, acc[rt][0][r], pa1[0]);
      pa1[1] = fmaf(a1v, acc[rt][1][r], pa1[1]);
      pa2[0] = fmaf(a2v, acc[rt][0][r], pa2[0]);
      pa2[1] = fmaf(a2v, acc[rt][1][r], pa2[1]);
    }
  }
#pragma unroll
  for (int cj = 0; cj < 2; cj++) {
    float v1 = pa1[cj], v2 = pa2[cj];
    v1 += __shfl_xor(v1, 16); v1 += __shfl_xor(v1, 32);
    v2 += __shfl_xor(v2, 16); v2 += __shfl_xor(v2, 32);
    if (lane < 16) {
      int n = n0 + (2 * w + cj) * 16 + lane;
      atomicAdd(&s1[(size_t)bh * N + n], v1);
      atomicAdd(&s2[(size_t)bh * N + n], v2);
    }
  }
}

// ========= out projection: hsT[b][f_out][n] = WoT . multi^T, + s1/s2 ======
// grid (4, 8, B), block 256. Tile 32 f_out x 64 n, K=1024.
__global__ __launch_bounds__(256) void k_proj_out_mfma(
    const short* __restrict__ WoT, const short* __restrict__ multi,
    const float* __restrict__ ao, short* __restrict__ hsT,
    float* __restrict__ s1, float* __restrict__ s2) {
  int ft = blockIdx.x, nt = blockIdx.y, b = blockIdx.z;
  constexpr int LK = 136;
  __shared__ short As[32 * LK];
  __shared__ short Bs[64 * LK];
  int tid = threadIdx.x, lane = tid & 63, w = tid >> 6;
  int arow = lane & 15, koff = (lane >> 4) * 8;
  const int KT = H * F;  // 1024
  f32x4 acc[2] = {};
  for (int k0 = 0; k0 < KT; k0 += 128) {
    __syncthreads();
    {  // A: 32 rows x 128 k
      int r = tid >> 3, e = tid & 7;
      const uint4* gp = (const uint4*)(WoT + (size_t)(ft * 32 + r) * KT + k0) + e * 2;
      uint4* lp = (uint4*)(As + r * LK) + e * 2;
      lp[0] = gp[0]; lp[1] = gp[1];
    }
    {  // B: 64 rows x 128 k
      int r = tid >> 2, q = tid & 3;
      const uint4* gp =
          (const uint4*)(multi + (size_t)(b * N + nt * 64 + r) * KT + k0) + q * 4;
      uint4* lp = (uint4*)(Bs + r * LK) + q * 4;
      lp[0] = gp[0]; lp[1] = gp[1]; lp[2] = gp[2]; lp[3] = gp[3];
    }
    __syncthreads();
#pragma unroll
    for (int ks = 0; ks < 4; ks++) {
      short8 b0 = *(const short8*)(Bs + (w * 16 + arow) * LK + ks * 32 + koff);
      short8 a0 = *(const short8*)(As + arow * LK + ks * 32 + koff);
      short8 a1 = *(const short8*)(As + (16 + arow) * LK + ks * 32 + koff);
      acc[0] = mfma16(a0, b0, acc[0]);
      acc[1] = mfma16(a1, b0, acc[1]);
    }
  }
  int crow0 = (lane >> 4) * 4;
  short* op = hsT + (size_t)b * F * N;
#pragma unroll
  for (int rt = 0; rt < 2; rt++)
#pragma unroll
    for (int r = 0; r < 4; r++)
      op[(size_t)(ft * 32 + rt * 16 + crow0 + r) * N + nt * 64 + w * 16 + arow] =
          f2bf(acc[rt][r]);
  // fused s1/s2 epilogue
  float pa1 = 0.f, pa2 = 0.f;
#pragma unroll
  for (int rt = 0; rt < 2; rt++) {
    int fo = ft * 32 + rt * 16 + crow0;
#pragma unroll
    for (int r = 0; r < 4; r++) {
      pa1 = fmaf(ao[fo + r], acc[rt][r], pa1);
      pa2 = fmaf(ao[F + fo + r], acc[rt][r], pa2);
    }
  }
  pa1 += __shfl_xor(pa1, 16); pa1 += __shfl_xor(pa1, 32);
  pa2 += __shfl_xor(pa2, 16); pa2 += __shfl_xor(pa2, 32);
  if (lane < 16) {
    int n = nt * 64 + w * 16 + lane;
    atomicAdd(&s1[(size_t)b * N + n], pa1);
    atomicAdd(&s2[(size_t)b * N + n], pa2);
  }
}

// ========= fused attention, 8 heads, single-pass softmax, ELU epilogue ====
// 64 Q-rows x 128 f per block; K-chunks of 128. grid (N/64, H, B), 256 thr.
__global__ __launch_bounds__(256) void k_attn_heads3(
    const short* __restrict__ VT, const float* __restrict__ s1g,
    const float* __restrict__ s2g, const unsigned long long* __restrict__ amask,
    short* __restrict__ multi) {
  int n0 = blockIdx.x * 64;
  int hd = blockIdx.y, b = blockIdx.z;
  int bh = b * H + hd;
  constexpr int LVK = 136;
  __shared__ short Vs[128 * LVK];
  __shared__ short Pf[16 * 64 * 8];  // 16 A-frags x 64 lanes x 8 bf16
  __shared__ float s2all[512];
  __shared__ float s1r[64], mrow[64], linv[64];
  __shared__ float red[64][4];

  int tid = threadIdx.x, lane = tid & 63, w = tid >> 6;
  s2all[tid] = s2g[(size_t)bh * N + tid];
  s2all[tid + 256] = s2g[(size_t)bh * N + tid + 256];
  if (tid < 64) s1r[tid] = s1g[(size_t)bh * N + n0 + tid];
  __syncthreads();
  // prepass: per-row masked max of s2 (LeakyReLU is monotone)
  {
    const unsigned long long* mq = amask + ((size_t)(b * N + n0 + lane)) * 8;
    float mx = FLOW;
#pragma unroll
    for (int j = 0; j < 2; j++) {
      unsigned long long mb = mq[w * 2 + j];
      int base = w * 128 + j * 64;
      unsigned lo = (unsigned)mb, hi = (unsigned)(mb >> 32);
#pragma unroll
      for (int k = 0; k < 32; k++) {
        mx = ((lo >> k) & 1u) ? fmaxf(mx, s2all[base + k]) : mx;
        mx = ((hi >> k) & 1u) ? fmaxf(mx, s2all[base + 32 + k]) : mx;
      }
    }
    red[lane][w] = mx;
  }
  __syncthreads();
  if (tid < 64) {
    float m2 = fmaxf(fmaxf(red[tid][0], red[tid][1]),
                     fmaxf(red[tid][2], red[tid][3]));
    float xm = s1r[tid] + m2;
    mrow[tid] = xm > 0.f ? xm : ALPHA_LR * xm;
  }
  float lp = 0.f;
  int arow = lane & 15, koff = (lane >> 4) * 8;
  f32x4 acc[4][2] = {};
  const short* Vg = VT + (size_t)bh * F * N;
  const unsigned long long* mp = amask + ((size_t)(b * N + n0 + lane)) * 8;
  for (int mc = 0; mc < 4; mc++) {
    int m0 = mc * 128;
    __syncthreads();  // prior MFMA done with Vs/Pf
    {                 // stage V^T chunk: 128 f x 128 m
      int fr = tid >> 1, hf = tid & 1;
      const uint4* g4 = (const uint4*)(Vg + (size_t)fr * N + m0 + hf * 64);
      uint4* l4 = (uint4*)(Vs + fr * LVK + hf * 64);
#pragma unroll
      for (int k = 0; k < 8; k++) l4[k] = g4[k];
    }
    {  // P: row = lane, k-range = w*32..+32, written in A-fragment order
      float s1v = s1r[lane], mr = mrow[lane];
      unsigned bits = (unsigned)(mp[mc * 2 + (w >> 1)] >> ((w & 1) * 32));
      short* pbase = Pf + (((lane >> 4) * 4 + w) * 64) * 8;
#pragma unroll
      for (int q = 0; q < 4; q++) {
        short8 pk;
#pragma unroll
        for (int j = 0; j < 8; j++) {
          float xv = s1v + s2all[m0 + w * 32 + q * 8 + j];
          xv = xv > 0.f ? xv : ALPHA_LR * xv;
          float p = __expf(xv - mr);
          p = ((bits >> (q * 8 + j)) & 1u) ? p : 0.f;
          lp += p;
          pk[j] = f2bf(p);
        }
        *(short8*)(pbase + ((q << 4) | (lane & 15)) * 8) = pk;
      }
    }
    __syncthreads();
#pragma unroll
    for (int ks = 0; ks < 4; ks++) {
      short8 a[4];
#pragma unroll
      for (int rt = 0; rt < 4; rt++)
        a[rt] = *(const short8*)(Pf + ((rt * 4 + ks) * 64 + lane) * 8);
#pragma unroll
      for (int cj = 0; cj < 2; cj++) {
        short8 bb = *(const short8*)(Vs + ((w * 2 + cj) * 16 + arow) * LVK +
                                     ks * 32 + koff);
#pragma unroll
        for (int rt = 0; rt < 4; rt++)
          acc[rt][cj] = mfma16(a[rt], bb, acc[rt][cj]);
      }
    }
  }
  __syncthreads();
  red[lane][w] = lp;
  __syncthreads();
  if (tid < 64)
    linv[tid] = 1.f / (red[tid][0] + red[tid][1] + red[tid][2] + red[tid][3]);
  __syncthreads();
  int crow0 = (lane >> 4) * 4;
#pragma unroll
  for (int rt = 0; rt < 4; rt++)
#pragma unroll
    for (int cj = 0; cj < 2; cj++) {
      int fcol = (w * 2 + cj) * 16 + arow;
#pragma unroll
      for (int rr = 0; rr < 4; rr++) {
        int nrow = rt * 16 + crow0 + rr;
        float v = acc[rt][cj][rr] * linv[nrow];
        v = v > 0.f ? v : __expf(v) - 1.f;  // ELU
        multi[((size_t)(b * N + n0 + nrow)) * (H * F) + hd * F + fcol] = f2bf(v);
      }
    }
}

// ========= fused attention single head + residual + LayerNorm =============
// 16 Q-rows x 128 f per block. grid (N/16, B), 256 thr.
template <int LAST>
__global__ __launch_bounds__(256) void k_attn_single3(
    const short* __restrict__ VT, const float* __restrict__ s1g,
    const float* __restrict__ s2g, const unsigned long long* __restrict__ amask,
    const float* __restrict__ resid, const float* __restrict__ lng,
    const float* __restrict__ lnb, float* __restrict__ hout,
    short* __restrict__ hbout, float* __restrict__ dout) {
  int n0 = blockIdx.x * 16;
  int b = blockIdx.y;
  constexpr int LVK = 136;
  __shared__ short Vs[128 * LVK];
  __shared__ short Pf[4 * 64 * 8];
  __shared__ float s2all[512];
  __shared__ float Ot[16][132];
  __shared__ float redS[16][16], redQ[16][16];
  __shared__ float s1r[16], mrow[16], linv[16], muA[16], rsA[16];

  int tid = threadIdx.x, lane = tid & 63, w = tid >> 6;
  s2all[tid] = s2g[(size_t)b * N + tid];
  s2all[tid + 256] = s2g[(size_t)b * N + tid + 256];
  if (tid < 16) s1r[tid] = s1g[(size_t)b * N + n0 + tid];
  __syncthreads();
  {  // prepass masked max: r = tid&15, seg = tid>>4 covers m [seg*32,+32)
    int r = tid & 15, seg = tid >> 4;
    unsigned long long mb = amask[((size_t)(b * N + n0 + r)) * 8 + (seg >> 1)];
    unsigned bits = (unsigned)(mb >> ((seg & 1) * 32));
    float mx = FLOW;
#pragma unroll
    for (int k = 0; k < 32; k++)
      mx = ((bits >> k) & 1u) ? fmaxf(mx, s2all[seg * 32 + k]) : mx;
    redS[r][seg] = mx;
  }
  __syncthreads();
  if (tid < 16) {
    float m2 = FLOW;
#pragma unroll
    for (int k = 0; k < 16; k++) m2 = fmaxf(m2, redS[tid][k]);
    float xm = s1r[tid] + m2;
    mrow[tid] = xm > 0.f ? xm : ALPHA_LR * xm;
  }
  float lp = 0.f;
  int arow = lane & 15, koff = (lane >> 4) * 8;
  int pr = tid & 15, pq = (tid >> 4) & 3;
  f32x4 acc[2] = {};
  const short* Vg = VT + (size_t)b * F * N;
  const unsigned long long* mp = amask + ((size_t)(b * N + n0 + pr)) * 8;
  for (int mc = 0; mc < 4; mc++) {
    int m0 = mc * 128;
    __syncthreads();
    {  // stage V^T chunk
      int fr = tid >> 1, hf = tid & 1;
      const uint4* g4 = (const uint4*)(Vg + (size_t)fr * N + m0 + hf * 64);
      uint4* l4 = (uint4*)(Vs + fr * LVK + hf * 64);
#pragma unroll
      for (int k = 0; k < 8; k++) l4[k] = g4[k];
    }
    {  // P: row pr, k = w*32 + pq*8 + j
      float s1v = s1r[pr], mr = mrow[pr];
      unsigned bits = (unsigned)(mp[mc * 2 + (w >> 1)] >> ((w & 1) * 32));
      short8 pk;
#pragma unroll
      for (int j = 0; j < 8; j++) {
        float xv = s1v + s2all[m0 + w * 32 + pq * 8 + j];
        xv = xv > 0.f ? xv : ALPHA_LR * xv;
        float p = __expf(xv - mr);
        p = ((bits >> (pq * 8 + j)) & 1u) ? p : 0.f;
        lp += p;
        pk[j] = f2bf(p);
      }
      *(short8*)(Pf + (w * 64 + ((pq << 4) | pr)) * 8) = pk;
    }
    __syncthreads();
#pragma unroll
    for (int ks = 0; ks < 4; ks++) {
      short8 a = *(const short8*)(Pf + (ks * 64 + lane) * 8);
#pragma unroll
      for (int cj = 0; cj < 2; cj++) {
        short8 bb = *(const short8*)(Vs + ((w * 2 + cj) * 16 + arow) * LVK +
                                     ks * 32 + koff);
        acc[cj] = mfma16(a, bb, acc[cj]);
      }
    }
  }
  __syncthreads();
  redS[pr][tid >> 4] = lp;
  __syncthreads();
  if (tid < 16) {
    float l = 0.f;
#pragma unroll
    for (int k = 0; k < 16; k++) l += redS[tid][k];
    linv[tid] = 1.f / l;
  }
  __syncthreads();
  int crow0 = (lane >> 4) * 4;
#pragma unroll
  for (int cj = 0; cj < 2; cj++) {
    int fcol = (w * 2 + cj) * 16 + arow;
#pragma unroll
    for (int rr = 0; rr < 4; rr++) {
      int row = crow0 + rr;
      Ot[row][fcol] = acc[cj][rr] * linv[row];
    }
  }
  __syncthreads();
  // LayerNorm over F=128: thread t owns (row = t>>4, 8 feats at (t&15)*8)
  int r2 = tid >> 4, f8 = (tid & 15) * 8;
  size_t gbase = ((size_t)(b * N + n0 + r2)) * F + f8;
  float v[8];
  float s = 0.f, sq = 0.f;
#pragma unroll
  for (int j = 0; j < 8; j++) {
    float t = Ot[r2][f8 + j] + resid[gbase + j];
    v[j] = t;
    s += t;
    sq = fmaf(t, t, sq);
  }
  redS[r2][tid & 15] = s;
  redQ[r2][tid & 15] = sq;
  __syncthreads();
  if (tid < 16) {
    float ss = 0.f, qq = 0.f;
#pragma unroll
    for (int k = 0; k < 16; k++) { ss += redS[tid][k]; qq += redQ[tid][k]; }
    float mu = ss * (1.f / F);
    muA[tid] = mu;
    rsA[tid] = rsqrtf(qq * (1.f / F) - mu * mu + EPS_LN);
  }
  __syncthreads();
  float mu = muA[r2], rs = rsA[r2];
#pragma unroll
  for (int j = 0; j < 8; j++) {
    float y = (v[j] - mu) * rs * lng[f8 + j] + lnb[f8 + j];
    if (LAST) {
      dout[gbase + j] = y;
    } else {
      y = fmaxf(y, 0.f);
      hout[gbase + j] = y;
      hbout[gbase + j] = f2bf(y);
    }
  }
}

extern "C" void kernel_launch(void* const* d_in, const int* in_sizes, int n_in,
                              void* d_out, int out_size, void* d_ws,
                              size_t ws_size, hipStream_t stream) {
  const float* x = (const float*)d_in[0];
  const int* adj = (const int*)d_in[1];
  const float* Wp = (const float*)d_in[2];
  const float* bp = (const float*)d_in[3];
  const float* W_heads = (const float*)d_in[4];
  const float* a_heads = (const float*)d_in[5];
  const float* W_out = (const float*)d_in[6];
  const float* a_out = (const float*)d_in[7];
  const float* ln_g = (const float*)d_in[8];
  const float* ln_b = (const float*)d_in[9];

  char* p = (char*)d_ws;
  auto alloc = [&](size_t bytes) {
    char* r = p;
    p += (bytes + 255) & ~(size_t)255;
    return r;
  };
  // s-buffers first (one contiguous memset): per layer s1h,s2h (32768 ea) +
  // s1o,s2o (4096 ea) = 73728 floats; x2 layers.
  float* sA = (float*)alloc((size_t)2 * 73728 * 4);
  short* WTh = (short*)alloc((size_t)2 * H * F * F * 2);
  short* WoT = (short*)alloc((size_t)2 * H * F * F * 2);
  unsigned long long* amask = (unsigned long long*)alloc((size_t)BN * 8 * 8);
  float* h = (float*)alloc((size_t)BN * F * 4);
  short* hb = (short*)alloc((size_t)BN * F * 2);
  short* hhT = (short*)alloc((size_t)B * H * F * N * 2);
  short* multi = (short*)alloc((size_t)BN * H * F * 2);
  short* hsT = (short*)alloc((size_t)B * F * N * 2);

  hipMemsetAsync(sA, 0, (size_t)2 * 73728 * 4, stream);
  k_setup<<<dim3(10752), 256, 0, stream>>>(x, adj, Wp, bp, W_heads, W_out, h,
                                           hb, amask, WTh, WoT);
  for (int l = 0; l < 2; l++) {
    float* s1h = sA + (size_t)l * 73728;
    float* s2h = s1h + 32768;
    float* s1o = s2h + 32768;
    float* s2o = s1o + 4096;
    k_proj_heads_mfma<<<dim3(4, 2, 64), 256, 0, stream>>>(
        WTh + (size_t)l * H * F * F, hb, a_heads + (size_t)l * H * 2 * F, hhT,
        s1h, s2h);
    k_attn_heads3<<<dim3(8, 8, 8), 256, 0, stream>>>(hhT, s1h, s2h, amask,
                                                     multi);
    k_proj_out_mfma<<<dim3(4, 8, 8), 256, 0, stream>>>(
        WoT + (size_t)l * F * H * F, multi, a_out + (size_t)l * 2 * F, hsT, s1o,
        s2o);
    if (l == 0)
      k_attn_single3<0><<<dim3(32, 8), 256, 0, stream>>>(
          hsT, s1o, s2o, amask, h, ln_g, ln_b, h, hb, nullptr);
    else
      k_attn_single3<1><<<dim3(32, 8), 256, 0, stream>>>(
          hsT, s1o, s2o, amask, h, ln_g + F, ln_b + F, nullptr, nullptr,
          (float*)d_out);
  }
}